// Round 7
// baseline (299.131 us; speedup 1.0000x reference)
//
#include <hip/hip_runtime.h>
#include <stdint.h>

typedef unsigned short ushort_t;
typedef __attribute__((ext_vector_type(8))) short bf16x8;   // 8 bf16 in 4 VGPRs
typedef __attribute__((ext_vector_type(4))) float f32x4;
typedef __attribute__((ext_vector_type(2))) float f32x2;

#define BKT_SHIFT 7
#define BKT_W     128
#define NB_MAX    1024
#define KB_THREADS 1024
#define KB_EPT    4
#define KB_CHUNK  (KB_THREADS * KB_EPT)   // 4096 edges per block, 16 waves
#define BCAP      2560               // lambda=2048, +11 sigma
#define CSTRIDE   2944               // BCAP + 128*3 pad headroom; multiple of 128
#define CSR_THREADS 512
#define PSLICES   1024               // R7: was 8 -> 1M atomics on 1024 addrs (~1000/addr
                                     // serialized, +29us). 1024 slices -> ~8 adds/addr.

// ---------------- helpers ----------------

__device__ __forceinline__ ushort_t f2bf(float f) {
    union { float f; uint32_t u; } a; a.f = f;
    uint32_t u = a.u;
    uint32_t r = (u + 0x7FFFu + ((u >> 16) & 1u)) >> 16;
    return (ushort_t)r;
}
__device__ __forceinline__ float bf_lo(uint32_t p) { return __uint_as_float(p << 16); }
__device__ __forceinline__ float bf_hi(uint32_t p) { return __uint_as_float(p & 0xFFFF0000u); }

// ---------------- kW_init: weight convert + zero small state + zero sentinel row ----------------
// blocks 0..63: weight transpose/convert. blocks 64..79: zero bcnt + pooled(512KB) + sentinel.
__global__ __launch_bounds__(256) void kW_init(const float* __restrict__ W1,
                                               const float* __restrict__ W2,
                                               ushort_t* __restrict__ Wt1,
                                               ushort_t* __restrict__ Wt2,
                                               int* __restrict__ bcnt,
                                               float* __restrict__ pooled,   // PSLICES*128
                                               uint8_t* __restrict__ xwq, int n) {
    int b = blockIdx.x, t = threadIdx.x;
    if (b < 64) {
        int i = b * 256 + t;
        int k = i >> 7, nn = i & 127;
        Wt1[nn * 128 + k] = f2bf(W1[i]);
        Wt2[nn * 128 + k] = f2bf(W2[i]);
    } else {
        const int tid = (b - 64) * 256 + t;
        const int zs = 16 * 256;
        for (int i = tid; i < PSLICES * 128; i += zs) pooled[i] = 0.f;
        for (int i = tid; i < NB_MAX; i += zs) bcnt[i] = 0;
        if (tid < 32) ((uint32_t*)(xwq + (size_t)n * 128))[tid] = 0u;   // sentinel zero-row
    }
}

// ---------------- kB_bucket: 1024-thread blocks, int4 edge loads, LDS histogram ----------------
__global__ __launch_bounds__(KB_THREADS) void kB_bucket(const int* __restrict__ src,
                                                        const int* __restrict__ dst, int E, int NB,
                                                        int* __restrict__ bcnt,
                                                        uint32_t* __restrict__ bpack) {
    __shared__ int lh[NB_MAX];
    const int t = threadIdx.x;
    for (int i = t; i < NB; i += KB_THREADS) lh[i] = 0;
    __syncthreads();

    const int base = blockIdx.x * KB_CHUNK + t * KB_EPT;
    int d[KB_EPT], rank[KB_EPT];
    const bool full = (base + KB_EPT - 1 < E);
    if (full) {
        int4 dv = *(const int4*)(dst + base);
        d[0] = dv.x; d[1] = dv.y; d[2] = dv.z; d[3] = dv.w;
#pragma unroll
        for (int i = 0; i < KB_EPT; i++)
            rank[i] = atomicAdd(&lh[d[i] >> BKT_SHIFT], 1);
    } else {
#pragma unroll
        for (int i = 0; i < KB_EPT; i++) {
            int e = base + i;
            if (e < E) {
                d[i] = dst[e];
                rank[i] = atomicAdd(&lh[d[i] >> BKT_SHIFT], 1);
            } else {
                d[i] = -1; rank[i] = 0;
            }
        }
    }
    __syncthreads();
    for (int i = t; i < NB; i += KB_THREADS) {
        int c = lh[i];
        lh[i] = c ? atomicAdd(&bcnt[i], c) : 0;
    }
    __syncthreads();
    if (full) {
        int4 sv = *(const int4*)(src + base);
        int s[KB_EPT] = {sv.x, sv.y, sv.z, sv.w};
#pragma unroll
        for (int i = 0; i < KB_EPT; i++) {
            int bkt = d[i] >> BKT_SHIFT;
            size_t pos = (size_t)bkt * BCAP + lh[bkt] + rank[i];
            bpack[pos] = ((uint32_t)s[i] << BKT_SHIFT) | (uint32_t)(d[i] & (BKT_W - 1));
        }
    } else {
#pragma unroll
        for (int i = 0; i < KB_EPT; i++) {
            if (d[i] >= 0) {
                int bkt = d[i] >> BKT_SHIFT;
                size_t pos = (size_t)bkt * BCAP + lh[bkt] + rank[i];
                bpack[pos] = ((uint32_t)src[base + i] << BKT_SHIFT) | (uint32_t)(d[i] & (BKT_W - 1));
            }
        }
    }
}

// ---------------- kC_csr: per-bucket CSR build, 4-padded segments, fixed-stride output ----------
__global__ __launch_bounds__(CSR_THREADS) void kC_csr(const uint32_t* __restrict__ bpack,
                                                      const int* __restrict__ bcnt, int NB, int n,
                                                      float* __restrict__ dinv,
                                                      int* __restrict__ offs,
                                                      int* __restrict__ ends,
                                                      int* __restrict__ csr) {
    __shared__ int pr[BKT_W];
    __shared__ int cnt[BKT_W];
    __shared__ int cur[BKT_W];
    __shared__ int pend[BKT_W];

    const int t = threadIdx.x;
    const int b = blockIdx.x;
    const int nb0 = b << BKT_SHIFT;
    const int wlen = min(BKT_W, n - nb0);
    const int cntb = bcnt[b];
    const uint32_t* bp = bpack + (size_t)b * BCAP;
    const int base = b * CSTRIDE;

    if (t < BKT_W) cnt[t] = 0;
    __syncthreads();
    for (int e = t; e < cntb; e += CSR_THREADS)
        atomicAdd(&cnt[bp[e] & (BKT_W - 1)], 1);
    __syncthreads();

    int v = (t < BKT_W) ? cnt[t] : 0;
    int pv = (v + 3) & ~3;                 // padded per-node length
    if (t < BKT_W) pr[t] = pv;
    __syncthreads();
    for (int off = 1; off < BKT_W; off <<= 1) {
        int x = (t >= off && t < BKT_W) ? pr[t - off] : 0;
        __syncthreads();
        if (t < BKT_W) pr[t] += x;
        __syncthreads();
    }
    if (t < BKT_W) {
        int st = base + pr[t] - pv;
        cur[t] = st;
        pend[t] = st + pv;
        if (t < wlen) {
            offs[nb0 + t] = st;
            ends[nb0 + t] = st + pv;
            dinv[nb0 + t] = rsqrtf((float)(v + 1));   // true count, not padded
        }
    }
    __syncthreads();

    for (int e = t; e < cntb; e += CSR_THREADS) {
        uint32_t p = bp[e];
        int pos = atomicAdd(&cur[p & (BKT_W - 1)], 1);
        csr[pos] = (int)(p >> BKT_SHIFT);
    }
    __syncthreads();
    if (t < BKT_W) {
        int qe = pend[t];
        for (int q = cur[t]; q < qe; q++) csr[q] = n;
    }
}

// ---------------- k_gemm1: layer-1 GEMM, f32 in (x), fp8 out (xw1), dinv-scaled ----------------
__global__ __launch_bounds__(256) void k_gemm1(const float* __restrict__ x,
                                               const ushort_t* __restrict__ Wt,
                                               const float* __restrict__ dinv,
                                               uint8_t* __restrict__ C, int n) {
    __shared__ ushort_t al[64 * 136];
    __shared__ ushort_t wl[128 * 136];
    const int t = threadIdx.x;
    const int l = t & 63;
    const int wave = t >> 6;
    const int lane15 = l & 15;
    const int quad = l >> 4;
    const int m0 = blockIdx.x * 64;
    const int rows = min(64, n - m0);

#pragma unroll
    for (int i = 0; i < 8; i++) {
        int f = t + 256 * i;
        int r = f >> 4, c = f & 15;
        *(uint4*)(&wl[r * 136 + c * 8]) = ((const uint4*)Wt)[f];
    }
    {
        const float4* Ap = (const float4*)(x + (size_t)m0 * 128);
        int nf = rows * 32;
#pragma unroll
        for (int i = 0; i < 8; i++) {
            int f = t + 256 * i;
            float4 vv = make_float4(0.f, 0.f, 0.f, 0.f);
            if (f < nf) vv = Ap[f];
            ushort4 us;
            us.x = f2bf(vv.x); us.y = f2bf(vv.y); us.z = f2bf(vv.z); us.w = f2bf(vv.w);
            int r = f >> 5, c = f & 31;
            *(ushort4*)(&al[r * 136 + c * 4]) = us;
        }
    }
    __syncthreads();

    f32x4 acc[8];
#pragma unroll
    for (int nt = 0; nt < 8; nt++) acc[nt] = (f32x4){0.f, 0.f, 0.f, 0.f};

    const int arow = wave * 16 + lane15;
#pragma unroll
    for (int kt = 0; kt < 4; kt++) {
        bf16x8 af = *(const bf16x8*)(&al[arow * 136 + kt * 32 + quad * 8]);
#pragma unroll
        for (int nt = 0; nt < 8; nt++) {
            bf16x8 bfr = *(const bf16x8*)(&wl[(nt * 16 + lane15) * 136 + kt * 32 + quad * 8]);
            acc[nt] = __builtin_amdgcn_mfma_f32_16x16x32_bf16(af, bfr, acc[nt], 0, 0, 0);
        }
    }

    const int rbase = m0 + wave * 16 + quad * 4;
    float dsc[4];
#pragma unroll
    for (int r = 0; r < 4; r++)
        dsc[r] = (rbase + r < n) ? dinv[rbase + r] : 0.f;
#pragma unroll
    for (int nt = 0; nt < 8; nt++) {
        int c0 = nt * 16 + lane15;
#pragma unroll
        for (int r = 0; r < 4; r += 2) {
            int pk = __builtin_amdgcn_cvt_pk_fp8_f32(acc[nt][r] * dsc[r],
                                                     acc[nt][r + 1] * dsc[r + 1], 0, false);
            int row0 = rbase + r, row1 = rbase + r + 1;
            if (row0 < n) C[(size_t)row0 * 128 + c0] = (uint8_t)pk;
            if (row1 < n) C[(size_t)row1 * 128 + c0] = (uint8_t)(pk >> 8);
        }
    }
}

// ---------------- MFMA GEMM (layer 2): bf16 in (h), fp8 out (xw2), dinv-scaled ----------------
__global__ __launch_bounds__(256) void k_gemm_mfma(const ushort_t* __restrict__ A,
                                                   const ushort_t* __restrict__ Wt,
                                                   const float* __restrict__ dinv,
                                                   uint8_t* __restrict__ C, int n) {
    __shared__ ushort_t al[64 * 136];
    __shared__ ushort_t wl[128 * 136];
    const int t = threadIdx.x;
    const int l = t & 63;
    const int wave = t >> 6;
    const int lane15 = l & 15;
    const int quad = l >> 4;
    const int m0 = blockIdx.x * 64;
    const int rows = min(64, n - m0);

#pragma unroll
    for (int i = 0; i < 8; i++) {
        int f = t + 256 * i;
        int r = f >> 4, c = f & 15;
        *(uint4*)(&wl[r * 136 + c * 8]) = ((const uint4*)Wt)[f];
    }
    {
        const uint4* Ap = (const uint4*)(A + (size_t)m0 * 128);
        int nf = rows * 16;
#pragma unroll
        for (int i = 0; i < 4; i++) {
            int f = t + 256 * i;
            uint4 v = make_uint4(0, 0, 0, 0);
            if (f < nf) v = Ap[f];
            int r = f >> 4, c = f & 15;
            *(uint4*)(&al[r * 136 + c * 8]) = v;
        }
    }
    __syncthreads();

    f32x4 acc[8];
#pragma unroll
    for (int nt = 0; nt < 8; nt++) acc[nt] = (f32x4){0.f, 0.f, 0.f, 0.f};

    const int arow = wave * 16 + lane15;
#pragma unroll
    for (int kt = 0; kt < 4; kt++) {
        bf16x8 af = *(const bf16x8*)(&al[arow * 136 + kt * 32 + quad * 8]);
#pragma unroll
        for (int nt = 0; nt < 8; nt++) {
            bf16x8 bfr = *(const bf16x8*)(&wl[(nt * 16 + lane15) * 136 + kt * 32 + quad * 8]);
            acc[nt] = __builtin_amdgcn_mfma_f32_16x16x32_bf16(af, bfr, acc[nt], 0, 0, 0);
        }
    }

    const int rbase = m0 + wave * 16 + quad * 4;
    float dsc[4];
#pragma unroll
    for (int r = 0; r < 4; r++)
        dsc[r] = (rbase + r < n) ? dinv[rbase + r] : 0.f;
#pragma unroll
    for (int nt = 0; nt < 8; nt++) {
        int c0 = nt * 16 + lane15;
#pragma unroll
        for (int r = 0; r < 4; r += 2) {
            int pk = __builtin_amdgcn_cvt_pk_fp8_f32(acc[nt][r] * dsc[r],
                                                     acc[nt][r + 1] * dsc[r + 1], 0, false);
            int row0 = rbase + r, row1 = rbase + r + 1;
            if (row0 < n) C[(size_t)row0 * 128 + c0] = (uint8_t)pk;
            if (row1 < n) C[(size_t)row1 * 128 + c0] = (uint8_t)(pk >> 8);
        }
    }
}

// ---------------- Aggregation: proven gather core; optional fused mean-pool epilogue ----------
// pooled != nullptr (layer-2 call): skip h write; block-reduce (ox,oy) and atomicAdd into
// slice blockIdx&(PSLICES-1). With PSLICES=1024 -> 8 blocks/slice -> ~8 adds per address.
__global__ __launch_bounds__(256) void k_agg(const ushort_t* __restrict__ xw,   // fp8 pairs
                                             const int* __restrict__ offsets,
                                             const int* __restrict__ ends,
                                             const int* __restrict__ csr,
                                             const float* __restrict__ dinv,
                                             const float* __restrict__ bias,
                                             ushort_t* __restrict__ out, int n,
                                             float* __restrict__ pooled) {
    __shared__ float red[512];
    const int l = threadIdx.x & 63;
    const int wave = (blockIdx.x << 2) | (threadIdx.x >> 6);
    const int wstride = gridDim.x << 2;
    const float2 bb = ((const float2*)bias)[l];
    uint32_t* out32 = (uint32_t*)out;
    float psx = 0.f, psy = 0.f;

    for (int v = wave; v < n; v += wstride) {
        uint32_t pv = (uint32_t)xw[(size_t)v * 64 + l];
        f32x2 fs = __builtin_amdgcn_cvt_pk_f32_fp8((int)pv, false);
        float ax = fs.x, ay = fs.y;

        int e  = __builtin_amdgcn_readfirstlane(offsets[v]);
        int e1 = __builtin_amdgcn_readfirstlane(ends[v]);

        for (; e + 15 < e1; e += 16) {
            const int4* c4 = (const int4*)(csr + e);
            int4 w0 = c4[0], w1 = c4[1], w2 = c4[2], w3 = c4[3];
            int u[16];
            u[0]  = __builtin_amdgcn_readfirstlane(w0.x);
            u[1]  = __builtin_amdgcn_readfirstlane(w0.y);
            u[2]  = __builtin_amdgcn_readfirstlane(w0.z);
            u[3]  = __builtin_amdgcn_readfirstlane(w0.w);
            u[4]  = __builtin_amdgcn_readfirstlane(w1.x);
            u[5]  = __builtin_amdgcn_readfirstlane(w1.y);
            u[6]  = __builtin_amdgcn_readfirstlane(w1.z);
            u[7]  = __builtin_amdgcn_readfirstlane(w1.w);
            u[8]  = __builtin_amdgcn_readfirstlane(w2.x);
            u[9]  = __builtin_amdgcn_readfirstlane(w2.y);
            u[10] = __builtin_amdgcn_readfirstlane(w2.z);
            u[11] = __builtin_amdgcn_readfirstlane(w2.w);
            u[12] = __builtin_amdgcn_readfirstlane(w3.x);
            u[13] = __builtin_amdgcn_readfirstlane(w3.y);
            u[14] = __builtin_amdgcn_readfirstlane(w3.z);
            u[15] = __builtin_amdgcn_readfirstlane(w3.w);
            uint32_t p[16];
#pragma unroll
            for (int i = 0; i < 16; i++) p[i] = (uint32_t)xw[(size_t)u[i] * 64 + l];
#pragma unroll
            for (int i = 0; i < 16; i++) {
                f32x2 f = __builtin_amdgcn_cvt_pk_f32_fp8((int)p[i], false);
                ax += f.x; ay += f.y;
            }
        }
        for (; e + 7 < e1; e += 8) {
            const int4* c4 = (const int4*)(csr + e);
            int4 w0 = c4[0], w1 = c4[1];
            int u[8];
            u[0] = __builtin_amdgcn_readfirstlane(w0.x);
            u[1] = __builtin_amdgcn_readfirstlane(w0.y);
            u[2] = __builtin_amdgcn_readfirstlane(w0.z);
            u[3] = __builtin_amdgcn_readfirstlane(w0.w);
            u[4] = __builtin_amdgcn_readfirstlane(w1.x);
            u[5] = __builtin_amdgcn_readfirstlane(w1.y);
            u[6] = __builtin_amdgcn_readfirstlane(w1.z);
            u[7] = __builtin_amdgcn_readfirstlane(w1.w);
            uint32_t p[8];
#pragma unroll
            for (int i = 0; i < 8; i++) p[i] = (uint32_t)xw[(size_t)u[i] * 64 + l];
#pragma unroll
            for (int i = 0; i < 8; i++) {
                f32x2 f = __builtin_amdgcn_cvt_pk_f32_fp8((int)p[i], false);
                ax += f.x; ay += f.y;
            }
        }
        for (; e + 3 < e1; e += 4) {
            int4 w0 = *(const int4*)(csr + e);
            int u[4];
            u[0] = __builtin_amdgcn_readfirstlane(w0.x);
            u[1] = __builtin_amdgcn_readfirstlane(w0.y);
            u[2] = __builtin_amdgcn_readfirstlane(w0.z);
            u[3] = __builtin_amdgcn_readfirstlane(w0.w);
            uint32_t p[4];
#pragma unroll
            for (int i = 0; i < 4; i++) p[i] = (uint32_t)xw[(size_t)u[i] * 64 + l];
#pragma unroll
            for (int i = 0; i < 4; i++) {
                f32x2 f = __builtin_amdgcn_cvt_pk_f32_fp8((int)p[i], false);
                ax += f.x; ay += f.y;
            }
        }

        float dv = dinv[v];
        float ox = fmaxf(fmaf(ax, dv, bb.x), 0.f);
        float oy = fmaxf(fmaf(ay, dv, bb.y), 0.f);
        if (pooled == nullptr) {
            out32[(size_t)v * 64 + l] = ((uint32_t)f2bf(oy) << 16) | (uint32_t)f2bf(ox);
        } else {
            psx += ox; psy += oy;
        }
    }

    if (pooled != nullptr) {
        const int t = threadIdx.x;
        red[t] = psx;
        red[256 + t] = psy;
        __syncthreads();
        if (t < 64) {
            float sx = red[t] + red[t + 64] + red[t + 128] + red[t + 192];
            float sy = red[256 + t] + red[256 + t + 64] + red[256 + t + 128] + red[256 + t + 192];
            float* slice = pooled + (size_t)(blockIdx.x & (PSLICES - 1)) * 128;
            atomicAdd(&slice[2 * t], sx);
            atomicAdd(&slice[2 * t + 1], sy);
        }
    }
}

// ---------------- k_fc: slice reduce (512KB coalesced) + final FC, one 512-thread block ------
__global__ __launch_bounds__(512) void k_fc(const float* __restrict__ pooled,
                                            const float* __restrict__ Wfc,
                                            const float* __restrict__ bfc,
                                            float* __restrict__ out, float invN) {
    __shared__ float red[512];
    __shared__ float pl[128];
    const int t = threadIdx.x;
    const int f = t & 127;
    const int g = t >> 7;          // 4 groups
    float acc = 0.f;
    for (int s = g; s < PSLICES; s += 4) acc += pooled[s * 128 + f];
    red[t] = acc;
    __syncthreads();
    if (t < 128) pl[t] = (red[t] + red[t + 128] + red[t + 256] + red[t + 384]) * invN;
    __syncthreads();
    if (t < 128) {
        float o = bfc[t];
#pragma unroll 8
        for (int k = 0; k < 128; k++) o = fmaf(pl[k], Wfc[k * 128 + t], o);
        out[t] = o;
    }
}

// ---------------- launcher ----------------
extern "C" void kernel_launch(void* const* d_in, const int* in_sizes, int n_in,
                              void* d_out, int out_size, void* d_ws, size_t ws_size,
                              hipStream_t stream) {
    const float* x    = (const float*)d_in[0];
    const int*   ei   = (const int*)d_in[1];
    const float* W1   = (const float*)d_in[2];
    const float* b1   = (const float*)d_in[3];
    const float* W2   = (const float*)d_in[4];
    const float* b2   = (const float*)d_in[5];
    const float* Wfc  = (const float*)d_in[6];
    const float* bfc  = (const float*)d_in[7];
    float*       out  = (float*)d_out;

    const int n = in_sizes[0] / 128;
    const int E = in_sizes[1] / 2;
    const int* src = ei;
    const int* dst = ei + E;
    const int NB = (n + BKT_W - 1) >> BKT_SHIFT;   // 782

    char* w = (char*)d_ws;
    uint8_t*  xwq = (uint8_t*)w;  w += (size_t)(n + 1) * 128;           // fp8 [n+1][128], row n = zeros
    ushort_t* h   = (ushort_t*)w; w += (size_t)n * 128 * sizeof(ushort_t);
    int*      csr = (int*)w;      w += (size_t)NB * CSTRIDE * sizeof(int);
    uint32_t* bpack = (uint32_t*)w; w += (size_t)NB * BCAP * sizeof(uint32_t);
    float* dinv = (float*)w;  w += (size_t)n * sizeof(float);
    int*   offs = (int*)w;    w += (size_t)n * sizeof(int);
    int*   ends = (int*)w;    w += (size_t)n * sizeof(int);
    w = (char*)(((uintptr_t)w + 127) & ~(uintptr_t)127);
    int*   bcnt  = (int*)w;   w += NB_MAX * sizeof(int);
    float* pooled = (float*)w; w += (size_t)PSLICES * 128 * sizeof(float);
    ushort_t* Wt1 = (ushort_t*)w; w += 16384 * sizeof(ushort_t);
    ushort_t* Wt2 = (ushort_t*)w; w += 16384 * sizeof(ushort_t);

    const int ntiles64 = (n + 63) / 64;
    const float invN = 1.0f / (float)n;

    kW_init<<<80, 256, 0, stream>>>(W1, W2, Wt1, Wt2, bcnt, pooled, xwq, n);
    kB_bucket<<<(E + KB_CHUNK - 1) / KB_CHUNK, KB_THREADS, 0, stream>>>(src, dst, E, NB, bcnt, bpack);
    kC_csr<<<NB, CSR_THREADS, 0, stream>>>(bpack, bcnt, NB, n, dinv, offs, ends, csr);
    k_gemm1<<<ntiles64, 256, 0, stream>>>(x, Wt1, dinv, xwq, n);

    k_agg<<<8192, 256, 0, stream>>>((const ushort_t*)xwq, offs, ends, csr, dinv, b1, h, n, nullptr);
    k_gemm_mfma<<<ntiles64, 256, 0, stream>>>(h, Wt2, dinv, xwq, n);
    k_agg<<<8192, 256, 0, stream>>>((const ushort_t*)xwq, offs, ends, csr, dinv, b2, h, n, pooled);

    k_fc<<<1, 512, 0, stream>>>(pooled, Wfc, bfc, out, invN);
}

// Round 8
// 240.431 us; speedup vs baseline: 1.2441x; 1.2441x over previous
//
#include <hip/hip_runtime.h>
#include <stdint.h>

typedef unsigned short ushort_t;
typedef __attribute__((ext_vector_type(8))) short bf16x8;   // 8 bf16 in 4 VGPRs
typedef __attribute__((ext_vector_type(4))) float f32x4;
typedef __attribute__((ext_vector_type(2))) float f32x2;

#define BKT_SHIFT 7
#define BKT_W     128
#define NB_MAX    1024
#define KB_THREADS 1024
#define KB_EPT    4
#define KB_CHUNK  (KB_THREADS * KB_EPT)   // 4096 edges per block, 16 waves
#define BCAP      2560               // lambda=2048, +11 sigma
#define CSTRIDE   2944               // BCAP + 128*3 pad headroom; multiple of 128
#define CSR_THREADS 512
#define PSLICES   1024               // 8 blocks/slice -> ~8 atomic adds per address

// ---------------- helpers ----------------

__device__ __forceinline__ ushort_t f2bf(float f) {
    union { float f; uint32_t u; } a; a.f = f;
    uint32_t u = a.u;
    uint32_t r = (u + 0x7FFFu + ((u >> 16) & 1u)) >> 16;
    return (ushort_t)r;
}
__device__ __forceinline__ float bf_lo(uint32_t p) { return __uint_as_float(p << 16); }
__device__ __forceinline__ float bf_hi(uint32_t p) { return __uint_as_float(p & 0xFFFF0000u); }

// ---------------- kW_init: weight convert + zero small state + zero sentinel row ----------------
__global__ __launch_bounds__(256) void kW_init(const float* __restrict__ W1,
                                               const float* __restrict__ W2,
                                               ushort_t* __restrict__ Wt1,
                                               ushort_t* __restrict__ Wt2,
                                               int* __restrict__ bcnt,
                                               float* __restrict__ pooled,   // PSLICES*128
                                               uint8_t* __restrict__ xwq, int n) {
    int b = blockIdx.x, t = threadIdx.x;
    if (b < 64) {
        int i = b * 256 + t;
        int k = i >> 7, nn = i & 127;
        Wt1[nn * 128 + k] = f2bf(W1[i]);
        Wt2[nn * 128 + k] = f2bf(W2[i]);
    } else {
        const int tid = (b - 64) * 256 + t;
        const int zs = 16 * 256;
        for (int i = tid; i < PSLICES * 128; i += zs) pooled[i] = 0.f;
        for (int i = tid; i < NB_MAX; i += zs) bcnt[i] = 0;
        if (tid < 32) ((uint32_t*)(xwq + (size_t)n * 128))[tid] = 0u;   // sentinel zero-row
    }
}

// ---------------- kB_bucket: 1024-thread blocks, int4 edge loads, LDS histogram ----------------
__global__ __launch_bounds__(KB_THREADS) void kB_bucket(const int* __restrict__ src,
                                                        const int* __restrict__ dst, int E, int NB,
                                                        int* __restrict__ bcnt,
                                                        uint32_t* __restrict__ bpack) {
    __shared__ int lh[NB_MAX];
    const int t = threadIdx.x;
    for (int i = t; i < NB; i += KB_THREADS) lh[i] = 0;
    __syncthreads();

    const int base = blockIdx.x * KB_CHUNK + t * KB_EPT;
    int d[KB_EPT], rank[KB_EPT];
    const bool full = (base + KB_EPT - 1 < E);
    if (full) {
        int4 dv = *(const int4*)(dst + base);
        d[0] = dv.x; d[1] = dv.y; d[2] = dv.z; d[3] = dv.w;
#pragma unroll
        for (int i = 0; i < KB_EPT; i++)
            rank[i] = atomicAdd(&lh[d[i] >> BKT_SHIFT], 1);
    } else {
#pragma unroll
        for (int i = 0; i < KB_EPT; i++) {
            int e = base + i;
            if (e < E) {
                d[i] = dst[e];
                rank[i] = atomicAdd(&lh[d[i] >> BKT_SHIFT], 1);
            } else {
                d[i] = -1; rank[i] = 0;
            }
        }
    }
    __syncthreads();
    for (int i = t; i < NB; i += KB_THREADS) {
        int c = lh[i];
        lh[i] = c ? atomicAdd(&bcnt[i], c) : 0;
    }
    __syncthreads();
    if (full) {
        int4 sv = *(const int4*)(src + base);
        int s[KB_EPT] = {sv.x, sv.y, sv.z, sv.w};
#pragma unroll
        for (int i = 0; i < KB_EPT; i++) {
            int bkt = d[i] >> BKT_SHIFT;
            size_t pos = (size_t)bkt * BCAP + lh[bkt] + rank[i];
            bpack[pos] = ((uint32_t)s[i] << BKT_SHIFT) | (uint32_t)(d[i] & (BKT_W - 1));
        }
    } else {
#pragma unroll
        for (int i = 0; i < KB_EPT; i++) {
            if (d[i] >= 0) {
                int bkt = d[i] >> BKT_SHIFT;
                size_t pos = (size_t)bkt * BCAP + lh[bkt] + rank[i];
                bpack[pos] = ((uint32_t)src[base + i] << BKT_SHIFT) | (uint32_t)(d[i] & (BKT_W - 1));
            }
        }
    }
}

// ---------------- kC_csr: per-bucket CSR build, 4-padded segments, fixed-stride output ----------
__global__ __launch_bounds__(CSR_THREADS) void kC_csr(const uint32_t* __restrict__ bpack,
                                                      const int* __restrict__ bcnt, int NB, int n,
                                                      float* __restrict__ dinv,
                                                      int* __restrict__ offs,
                                                      int* __restrict__ ends,
                                                      int* __restrict__ csr) {
    __shared__ int pr[BKT_W];
    __shared__ int cnt[BKT_W];
    __shared__ int cur[BKT_W];
    __shared__ int pend[BKT_W];

    const int t = threadIdx.x;
    const int b = blockIdx.x;
    const int nb0 = b << BKT_SHIFT;
    const int wlen = min(BKT_W, n - nb0);
    const int cntb = bcnt[b];
    const uint32_t* bp = bpack + (size_t)b * BCAP;
    const int base = b * CSTRIDE;

    if (t < BKT_W) cnt[t] = 0;
    __syncthreads();
    for (int e = t; e < cntb; e += CSR_THREADS)
        atomicAdd(&cnt[bp[e] & (BKT_W - 1)], 1);
    __syncthreads();

    int v = (t < BKT_W) ? cnt[t] : 0;
    int pv = (v + 3) & ~3;                 // padded per-node length
    if (t < BKT_W) pr[t] = pv;
    __syncthreads();
    for (int off = 1; off < BKT_W; off <<= 1) {
        int x = (t >= off && t < BKT_W) ? pr[t - off] : 0;
        __syncthreads();
        if (t < BKT_W) pr[t] += x;
        __syncthreads();
    }
    if (t < BKT_W) {
        int st = base + pr[t] - pv;
        cur[t] = st;
        pend[t] = st + pv;
        if (t < wlen) {
            offs[nb0 + t] = st;
            ends[nb0 + t] = st + pv;
            dinv[nb0 + t] = rsqrtf((float)(v + 1));   // true count, not padded
        }
    }
    __syncthreads();

    for (int e = t; e < cntb; e += CSR_THREADS) {
        uint32_t p = bp[e];
        int pos = atomicAdd(&cur[p & (BKT_W - 1)], 1);
        csr[pos] = (int)(p >> BKT_SHIFT);
    }
    __syncthreads();
    if (t < BKT_W) {
        int qe = pend[t];
        for (int q = cur[t]; q < qe; q++) csr[q] = n;
    }
}

// ---------------- k_gemm1: layer-1 GEMM, f32 in (x), fp8 out (xw1), dinv-scaled ----------------
__global__ __launch_bounds__(256) void k_gemm1(const float* __restrict__ x,
                                               const ushort_t* __restrict__ Wt,
                                               const float* __restrict__ dinv,
                                               uint8_t* __restrict__ C, int n) {
    __shared__ ushort_t al[64 * 136];
    __shared__ ushort_t wl[128 * 136];
    const int t = threadIdx.x;
    const int l = t & 63;
    const int wave = t >> 6;
    const int lane15 = l & 15;
    const int quad = l >> 4;
    const int m0 = blockIdx.x * 64;
    const int rows = min(64, n - m0);

#pragma unroll
    for (int i = 0; i < 8; i++) {
        int f = t + 256 * i;
        int r = f >> 4, c = f & 15;
        *(uint4*)(&wl[r * 136 + c * 8]) = ((const uint4*)Wt)[f];
    }
    {
        const float4* Ap = (const float4*)(x + (size_t)m0 * 128);
        int nf = rows * 32;
#pragma unroll
        for (int i = 0; i < 8; i++) {
            int f = t + 256 * i;
            float4 vv = make_float4(0.f, 0.f, 0.f, 0.f);
            if (f < nf) vv = Ap[f];
            ushort4 us;
            us.x = f2bf(vv.x); us.y = f2bf(vv.y); us.z = f2bf(vv.z); us.w = f2bf(vv.w);
            int r = f >> 5, c = f & 31;
            *(ushort4*)(&al[r * 136 + c * 4]) = us;
        }
    }
    __syncthreads();

    f32x4 acc[8];
#pragma unroll
    for (int nt = 0; nt < 8; nt++) acc[nt] = (f32x4){0.f, 0.f, 0.f, 0.f};

    const int arow = wave * 16 + lane15;
#pragma unroll
    for (int kt = 0; kt < 4; kt++) {
        bf16x8 af = *(const bf16x8*)(&al[arow * 136 + kt * 32 + quad * 8]);
#pragma unroll
        for (int nt = 0; nt < 8; nt++) {
            bf16x8 bfr = *(const bf16x8*)(&wl[(nt * 16 + lane15) * 136 + kt * 32 + quad * 8]);
            acc[nt] = __builtin_amdgcn_mfma_f32_16x16x32_bf16(af, bfr, acc[nt], 0, 0, 0);
        }
    }

    const int rbase = m0 + wave * 16 + quad * 4;
    float dsc[4];
#pragma unroll
    for (int r = 0; r < 4; r++)
        dsc[r] = (rbase + r < n) ? dinv[rbase + r] : 0.f;
#pragma unroll
    for (int nt = 0; nt < 8; nt++) {
        int c0 = nt * 16 + lane15;
#pragma unroll
        for (int r = 0; r < 4; r += 2) {
            int pk = __builtin_amdgcn_cvt_pk_fp8_f32(acc[nt][r] * dsc[r],
                                                     acc[nt][r + 1] * dsc[r + 1], 0, false);
            int row0 = rbase + r, row1 = rbase + r + 1;
            if (row0 < n) C[(size_t)row0 * 128 + c0] = (uint8_t)pk;
            if (row1 < n) C[(size_t)row1 * 128 + c0] = (uint8_t)(pk >> 8);
        }
    }
}

// ---------------- MFMA GEMM (layer 2): bf16 in (h), fp8 out (xw2), dinv-scaled ----------------
__global__ __launch_bounds__(256) void k_gemm_mfma(const ushort_t* __restrict__ A,
                                                   const ushort_t* __restrict__ Wt,
                                                   const float* __restrict__ dinv,
                                                   uint8_t* __restrict__ C, int n) {
    __shared__ ushort_t al[64 * 136];
    __shared__ ushort_t wl[128 * 136];
    const int t = threadIdx.x;
    const int l = t & 63;
    const int wave = t >> 6;
    const int lane15 = l & 15;
    const int quad = l >> 4;
    const int m0 = blockIdx.x * 64;
    const int rows = min(64, n - m0);

#pragma unroll
    for (int i = 0; i < 8; i++) {
        int f = t + 256 * i;
        int r = f >> 4, c = f & 15;
        *(uint4*)(&wl[r * 136 + c * 8]) = ((const uint4*)Wt)[f];
    }
    {
        const uint4* Ap = (const uint4*)(A + (size_t)m0 * 128);
        int nf = rows * 16;
#pragma unroll
        for (int i = 0; i < 4; i++) {
            int f = t + 256 * i;
            uint4 v = make_uint4(0, 0, 0, 0);
            if (f < nf) v = Ap[f];
            int r = f >> 4, c = f & 15;
            *(uint4*)(&al[r * 136 + c * 8]) = v;
        }
    }
    __syncthreads();

    f32x4 acc[8];
#pragma unroll
    for (int nt = 0; nt < 8; nt++) acc[nt] = (f32x4){0.f, 0.f, 0.f, 0.f};

    const int arow = wave * 16 + lane15;
#pragma unroll
    for (int kt = 0; kt < 4; kt++) {
        bf16x8 af = *(const bf16x8*)(&al[arow * 136 + kt * 32 + quad * 8]);
#pragma unroll
        for (int nt = 0; nt < 8; nt++) {
            bf16x8 bfr = *(const bf16x8*)(&wl[(nt * 16 + lane15) * 136 + kt * 32 + quad * 8]);
            acc[nt] = __builtin_amdgcn_mfma_f32_16x16x32_bf16(af, bfr, acc[nt], 0, 0, 0);
        }
    }

    const int rbase = m0 + wave * 16 + quad * 4;
    float dsc[4];
#pragma unroll
    for (int r = 0; r < 4; r++)
        dsc[r] = (rbase + r < n) ? dinv[rbase + r] : 0.f;
#pragma unroll
    for (int nt = 0; nt < 8; nt++) {
        int c0 = nt * 16 + lane15;
#pragma unroll
        for (int r = 0; r < 4; r += 2) {
            int pk = __builtin_amdgcn_cvt_pk_fp8_f32(acc[nt][r] * dsc[r],
                                                     acc[nt][r + 1] * dsc[r + 1], 0, false);
            int row0 = rbase + r, row1 = rbase + r + 1;
            if (row0 < n) C[(size_t)row0 * 128 + c0] = (uint8_t)pk;
            if (row1 < n) C[(size_t)row1 * 128 + c0] = (uint8_t)(pk >> 8);
        }
    }
}

// ---------------- Aggregation: proven gather core; optional fused mean-pool epilogue ----------
__global__ __launch_bounds__(256) void k_agg(const ushort_t* __restrict__ xw,   // fp8 pairs
                                             const int* __restrict__ offsets,
                                             const int* __restrict__ ends,
                                             const int* __restrict__ csr,
                                             const float* __restrict__ dinv,
                                             const float* __restrict__ bias,
                                             ushort_t* __restrict__ out, int n,
                                             float* __restrict__ pooled) {
    __shared__ float red[512];
    const int l = threadIdx.x & 63;
    const int wave = (blockIdx.x << 2) | (threadIdx.x >> 6);
    const int wstride = gridDim.x << 2;
    const float2 bb = ((const float2*)bias)[l];
    uint32_t* out32 = (uint32_t*)out;
    float psx = 0.f, psy = 0.f;

    for (int v = wave; v < n; v += wstride) {
        uint32_t pv = (uint32_t)xw[(size_t)v * 64 + l];
        f32x2 fs = __builtin_amdgcn_cvt_pk_f32_fp8((int)pv, false);
        float ax = fs.x, ay = fs.y;

        int e  = __builtin_amdgcn_readfirstlane(offsets[v]);
        int e1 = __builtin_amdgcn_readfirstlane(ends[v]);

        for (; e + 15 < e1; e += 16) {
            const int4* c4 = (const int4*)(csr + e);
            int4 w0 = c4[0], w1 = c4[1], w2 = c4[2], w3 = c4[3];
            int u[16];
            u[0]  = __builtin_amdgcn_readfirstlane(w0.x);
            u[1]  = __builtin_amdgcn_readfirstlane(w0.y);
            u[2]  = __builtin_amdgcn_readfirstlane(w0.z);
            u[3]  = __builtin_amdgcn_readfirstlane(w0.w);
            u[4]  = __builtin_amdgcn_readfirstlane(w1.x);
            u[5]  = __builtin_amdgcn_readfirstlane(w1.y);
            u[6]  = __builtin_amdgcn_readfirstlane(w1.z);
            u[7]  = __builtin_amdgcn_readfirstlane(w1.w);
            u[8]  = __builtin_amdgcn_readfirstlane(w2.x);
            u[9]  = __builtin_amdgcn_readfirstlane(w2.y);
            u[10] = __builtin_amdgcn_readfirstlane(w2.z);
            u[11] = __builtin_amdgcn_readfirstlane(w2.w);
            u[12] = __builtin_amdgcn_readfirstlane(w3.x);
            u[13] = __builtin_amdgcn_readfirstlane(w3.y);
            u[14] = __builtin_amdgcn_readfirstlane(w3.z);
            u[15] = __builtin_amdgcn_readfirstlane(w3.w);
            uint32_t p[16];
#pragma unroll
            for (int i = 0; i < 16; i++) p[i] = (uint32_t)xw[(size_t)u[i] * 64 + l];
#pragma unroll
            for (int i = 0; i < 16; i++) {
                f32x2 f = __builtin_amdgcn_cvt_pk_f32_fp8((int)p[i], false);
                ax += f.x; ay += f.y;
            }
        }
        for (; e + 7 < e1; e += 8) {
            const int4* c4 = (const int4*)(csr + e);
            int4 w0 = c4[0], w1 = c4[1];
            int u[8];
            u[0] = __builtin_amdgcn_readfirstlane(w0.x);
            u[1] = __builtin_amdgcn_readfirstlane(w0.y);
            u[2] = __builtin_amdgcn_readfirstlane(w0.z);
            u[3] = __builtin_amdgcn_readfirstlane(w0.w);
            u[4] = __builtin_amdgcn_readfirstlane(w1.x);
            u[5] = __builtin_amdgcn_readfirstlane(w1.y);
            u[6] = __builtin_amdgcn_readfirstlane(w1.z);
            u[7] = __builtin_amdgcn_readfirstlane(w1.w);
            uint32_t p[8];
#pragma unroll
            for (int i = 0; i < 8; i++) p[i] = (uint32_t)xw[(size_t)u[i] * 64 + l];
#pragma unroll
            for (int i = 0; i < 8; i++) {
                f32x2 f = __builtin_amdgcn_cvt_pk_f32_fp8((int)p[i], false);
                ax += f.x; ay += f.y;
            }
        }
        for (; e + 3 < e1; e += 4) {
            int4 w0 = *(const int4*)(csr + e);
            int u[4];
            u[0] = __builtin_amdgcn_readfirstlane(w0.x);
            u[1] = __builtin_amdgcn_readfirstlane(w0.y);
            u[2] = __builtin_amdgcn_readfirstlane(w0.z);
            u[3] = __builtin_amdgcn_readfirstlane(w0.w);
            uint32_t p[4];
#pragma unroll
            for (int i = 0; i < 4; i++) p[i] = (uint32_t)xw[(size_t)u[i] * 64 + l];
#pragma unroll
            for (int i = 0; i < 4; i++) {
                f32x2 f = __builtin_amdgcn_cvt_pk_f32_fp8((int)p[i], false);
                ax += f.x; ay += f.y;
            }
        }

        float dv = dinv[v];
        float ox = fmaxf(fmaf(ax, dv, bb.x), 0.f);
        float oy = fmaxf(fmaf(ay, dv, bb.y), 0.f);
        if (pooled == nullptr) {
            out32[(size_t)v * 64 + l] = ((uint32_t)f2bf(oy) << 16) | (uint32_t)f2bf(ox);
        } else {
            psx += ox; psy += oy;
        }
    }

    if (pooled != nullptr) {
        const int t = threadIdx.x;
        red[t] = psx;
        red[256 + t] = psy;
        __syncthreads();
        if (t < 64) {
            float sx = red[t] + red[t + 64] + red[t + 128] + red[t + 192];
            float sy = red[256 + t] + red[256 + t + 64] + red[256 + t + 128] + red[256 + t + 192];
            float* slice = pooled + (size_t)(blockIdx.x & (PSLICES - 1)) * 128;
            atomicAdd(&slice[2 * t], sx);
            atomicAdd(&slice[2 * t + 1], sy);
        }
    }
}

// ---------------- k_fc: ILP'd slice reduce + LDS-staged FC, one 512-thread block ------
// R8: was a serial dependent-load chain (12 VGPR, 256 x ~400cyc = 43us). Now: thread t owns
// feature-quad q=t&31, slice-group g=t>>5; 64 independent f32x4 loads into 4 accumulators
// (latency-hidden), LDS group-reduce, Wfc staged to LDS (64KB, coalesced), FC from LDS.
__global__ __launch_bounds__(512) void k_fc(const float* __restrict__ pooled,
                                            const float* __restrict__ Wfc,
                                            const float* __restrict__ bfc,
                                            float* __restrict__ out, float invN) {
    __shared__ f32x4 red4[512];        // 8 KB
    __shared__ float pl[128];
    __shared__ float wf[128 * 128];    // 64 KB
    const int t = threadIdx.x;
    const int q = t & 31;              // feature quad (features 4q..4q+3)
    const int g = t >> 5;              // slice group, 16 groups

    // stage Wfc -> LDS (4096 f32x4, coalesced, independent of reduction)
    const f32x4* W4 = (const f32x4*)Wfc;
    f32x4* wf4 = (f32x4*)wf;
#pragma unroll
    for (int i = 0; i < 8; i++) wf4[t + 512 * i] = W4[t + 512 * i];

    // slice reduce: group g sums slices {g, g+16, ..., g+16*63}
    const f32x4* P = (const f32x4*)pooled;   // [PSLICES][32]
    f32x4 a0 = (f32x4){0.f, 0.f, 0.f, 0.f}, a1 = a0, a2 = a0, a3 = a0;
#pragma unroll
    for (int k = 0; k < 16; k++) {
        a0 += P[(size_t)(g + 16 * (4 * k + 0)) * 32 + q];
        a1 += P[(size_t)(g + 16 * (4 * k + 1)) * 32 + q];
        a2 += P[(size_t)(g + 16 * (4 * k + 2)) * 32 + q];
        a3 += P[(size_t)(g + 16 * (4 * k + 3)) * 32 + q];
    }
    red4[t] = (a0 + a1) + (a2 + a3);
    __syncthreads();
    if (t < 32) {
        f32x4 s = red4[t];
#pragma unroll
        for (int g2 = 1; g2 < 16; g2++) s += red4[g2 * 32 + t];
        pl[4 * t + 0] = s[0] * invN;
        pl[4 * t + 1] = s[1] * invN;
        pl[4 * t + 2] = s[2] * invN;
        pl[4 * t + 3] = s[3] * invN;
    }
    __syncthreads();
    if (t < 128) {
        float o = bfc[t];
#pragma unroll 8
        for (int k = 0; k < 128; k++) o = fmaf(pl[k], wf[k * 128 + t], o);
        out[t] = o;
    }
}

// ---------------- launcher ----------------
extern "C" void kernel_launch(void* const* d_in, const int* in_sizes, int n_in,
                              void* d_out, int out_size, void* d_ws, size_t ws_size,
                              hipStream_t stream) {
    const float* x    = (const float*)d_in[0];
    const int*   ei   = (const int*)d_in[1];
    const float* W1   = (const float*)d_in[2];
    const float* b1   = (const float*)d_in[3];
    const float* W2   = (const float*)d_in[4];
    const float* b2   = (const float*)d_in[5];
    const float* Wfc  = (const float*)d_in[6];
    const float* bfc  = (const float*)d_in[7];
    float*       out  = (float*)d_out;

    const int n = in_sizes[0] / 128;
    const int E = in_sizes[1] / 2;
    const int* src = ei;
    const int* dst = ei + E;
    const int NB = (n + BKT_W - 1) >> BKT_SHIFT;   // 782

    char* w = (char*)d_ws;
    uint8_t*  xwq = (uint8_t*)w;  w += (size_t)(n + 1) * 128;           // fp8 [n+1][128], row n = zeros
    ushort_t* h   = (ushort_t*)w; w += (size_t)n * 128 * sizeof(ushort_t);
    int*      csr = (int*)w;      w += (size_t)NB * CSTRIDE * sizeof(int);
    uint32_t* bpack = (uint32_t*)w; w += (size_t)NB * BCAP * sizeof(uint32_t);
    float* dinv = (float*)w;  w += (size_t)n * sizeof(float);
    int*   offs = (int*)w;    w += (size_t)n * sizeof(int);
    int*   ends = (int*)w;    w += (size_t)n * sizeof(int);
    w = (char*)(((uintptr_t)w + 127) & ~(uintptr_t)127);
    int*   bcnt  = (int*)w;   w += NB_MAX * sizeof(int);
    float* pooled = (float*)w; w += (size_t)PSLICES * 128 * sizeof(float);
    ushort_t* Wt1 = (ushort_t*)w; w += 16384 * sizeof(ushort_t);
    ushort_t* Wt2 = (ushort_t*)w; w += 16384 * sizeof(ushort_t);

    const int ntiles64 = (n + 63) / 64;
    const float invN = 1.0f / (float)n;

    kW_init<<<80, 256, 0, stream>>>(W1, W2, Wt1, Wt2, bcnt, pooled, xwq, n);
    kB_bucket<<<(E + KB_CHUNK - 1) / KB_CHUNK, KB_THREADS, 0, stream>>>(src, dst, E, NB, bcnt, bpack);
    kC_csr<<<NB, CSR_THREADS, 0, stream>>>(bpack, bcnt, NB, n, dinv, offs, ends, csr);
    k_gemm1<<<ntiles64, 256, 0, stream>>>(x, Wt1, dinv, xwq, n);

    k_agg<<<8192, 256, 0, stream>>>((const ushort_t*)xwq, offs, ends, csr, dinv, b1, h, n, nullptr);
    k_gemm_mfma<<<ntiles64, 256, 0, stream>>>(h, Wt2, dinv, xwq, n);
    k_agg<<<8192, 256, 0, stream>>>((const ushort_t*)xwq, offs, ends, csr, dinv, b2, h, n, pooled);

    k_fc<<<1, 512, 0, stream>>>(pooled, Wfc, bfc, out, invN);
}

// Round 9
// 239.269 us; speedup vs baseline: 1.2502x; 1.0049x over previous
//
#include <hip/hip_runtime.h>
#include <stdint.h>

typedef unsigned short ushort_t;
typedef __attribute__((ext_vector_type(8))) short bf16x8;   // 8 bf16 in 4 VGPRs
typedef __attribute__((ext_vector_type(4))) float f32x4;
typedef __attribute__((ext_vector_type(2))) float f32x2;

#define BKT_SHIFT 7
#define BKT_W     128
#define NB_MAX    1024
#define KB_THREADS 1024
#define KB_EPT    4
#define KB_CHUNK  (KB_THREADS * KB_EPT)   // 4096 edges per block, 16 waves
#define BCAP      2560               // lambda=2048, +11 sigma
#define CSTRIDE   2944               // BCAP + 128*3 pad headroom; multiple of 128
#define CSR_THREADS 512
#define PSLICES   1024               // 8 blocks/slice -> ~8 atomic adds per address

// ---------------- helpers ----------------

__device__ __forceinline__ ushort_t f2bf(float f) {
    union { float f; uint32_t u; } a; a.f = f;
    uint32_t u = a.u;
    uint32_t r = (u + 0x7FFFu + ((u >> 16) & 1u)) >> 16;
    return (ushort_t)r;
}
__device__ __forceinline__ float bf_lo(uint32_t p) { return __uint_as_float(p << 16); }
__device__ __forceinline__ float bf_hi(uint32_t p) { return __uint_as_float(p & 0xFFFF0000u); }

// ---------------- kW_init: weight convert + zero small state + zero sentinel row ----------------
__global__ __launch_bounds__(256) void kW_init(const float* __restrict__ W1,
                                               const float* __restrict__ W2,
                                               ushort_t* __restrict__ Wt1,
                                               ushort_t* __restrict__ Wt2,
                                               int* __restrict__ bcnt,
                                               float* __restrict__ pooled,   // PSLICES*128
                                               uint8_t* __restrict__ xwq,
                                               int* __restrict__ oe, int n) {
    int b = blockIdx.x, t = threadIdx.x;
    if (b < 64) {
        int i = b * 256 + t;
        int k = i >> 7, nn = i & 127;
        Wt1[nn * 128 + k] = f2bf(W1[i]);
        Wt2[nn * 128 + k] = f2bf(W2[i]);
    } else {
        const int tid = (b - 64) * 256 + t;
        const int zs = 16 * 256;
        for (int i = tid; i < PSLICES * 128; i += zs) pooled[i] = 0.f;
        for (int i = tid; i < NB_MAX; i += zs) bcnt[i] = 0;
        if (tid < 32) ((uint32_t*)(xwq + (size_t)n * 128))[tid] = 0u;   // sentinel zero-row
        if (tid < 16) oe[2 * n + tid] = 0;                              // oe tail: e=e1=0
    }
}

// ---------------- kB_bucket: 1024-thread blocks, int4 edge loads, LDS histogram ----------------
__global__ __launch_bounds__(KB_THREADS) void kB_bucket(const int* __restrict__ src,
                                                        const int* __restrict__ dst, int E, int NB,
                                                        int* __restrict__ bcnt,
                                                        uint32_t* __restrict__ bpack) {
    __shared__ int lh[NB_MAX];
    const int t = threadIdx.x;
    for (int i = t; i < NB; i += KB_THREADS) lh[i] = 0;
    __syncthreads();

    const int base = blockIdx.x * KB_CHUNK + t * KB_EPT;
    int d[KB_EPT], rank[KB_EPT];
    const bool full = (base + KB_EPT - 1 < E);
    if (full) {
        int4 dv = *(const int4*)(dst + base);
        d[0] = dv.x; d[1] = dv.y; d[2] = dv.z; d[3] = dv.w;
#pragma unroll
        for (int i = 0; i < KB_EPT; i++)
            rank[i] = atomicAdd(&lh[d[i] >> BKT_SHIFT], 1);
    } else {
#pragma unroll
        for (int i = 0; i < KB_EPT; i++) {
            int e = base + i;
            if (e < E) {
                d[i] = dst[e];
                rank[i] = atomicAdd(&lh[d[i] >> BKT_SHIFT], 1);
            } else {
                d[i] = -1; rank[i] = 0;
            }
        }
    }
    __syncthreads();
    for (int i = t; i < NB; i += KB_THREADS) {
        int c = lh[i];
        lh[i] = c ? atomicAdd(&bcnt[i], c) : 0;
    }
    __syncthreads();
    if (full) {
        int4 sv = *(const int4*)(src + base);
        int s[KB_EPT] = {sv.x, sv.y, sv.z, sv.w};
#pragma unroll
        for (int i = 0; i < KB_EPT; i++) {
            int bkt = d[i] >> BKT_SHIFT;
            size_t pos = (size_t)bkt * BCAP + lh[bkt] + rank[i];
            bpack[pos] = ((uint32_t)s[i] << BKT_SHIFT) | (uint32_t)(d[i] & (BKT_W - 1));
        }
    } else {
#pragma unroll
        for (int i = 0; i < KB_EPT; i++) {
            if (d[i] >= 0) {
                int bkt = d[i] >> BKT_SHIFT;
                size_t pos = (size_t)bkt * BCAP + lh[bkt] + rank[i];
                bpack[pos] = ((uint32_t)src[base + i] << BKT_SHIFT) | (uint32_t)(d[i] & (BKT_W - 1));
            }
        }
    }
}

// ---------------- kC_csr: per-bucket CSR build, 4-padded segments, interleaved oe pairs --------
__global__ __launch_bounds__(CSR_THREADS) void kC_csr(const uint32_t* __restrict__ bpack,
                                                      const int* __restrict__ bcnt, int NB, int n,
                                                      float* __restrict__ dinv,
                                                      int* __restrict__ oe,
                                                      int* __restrict__ csr) {
    __shared__ int pr[BKT_W];
    __shared__ int cnt[BKT_W];
    __shared__ int cur[BKT_W];
    __shared__ int pend[BKT_W];

    const int t = threadIdx.x;
    const int b = blockIdx.x;
    const int nb0 = b << BKT_SHIFT;
    const int wlen = min(BKT_W, n - nb0);
    const int cntb = bcnt[b];
    const uint32_t* bp = bpack + (size_t)b * BCAP;
    const int base = b * CSTRIDE;

    if (t < BKT_W) cnt[t] = 0;
    __syncthreads();
    for (int e = t; e < cntb; e += CSR_THREADS)
        atomicAdd(&cnt[bp[e] & (BKT_W - 1)], 1);
    __syncthreads();

    int v = (t < BKT_W) ? cnt[t] : 0;
    int pv = (v + 3) & ~3;                 // padded per-node length
    if (t < BKT_W) pr[t] = pv;
    __syncthreads();
    for (int off = 1; off < BKT_W; off <<= 1) {
        int x = (t >= off && t < BKT_W) ? pr[t - off] : 0;
        __syncthreads();
        if (t < BKT_W) pr[t] += x;
        __syncthreads();
    }
    if (t < BKT_W) {
        int st = base + pr[t] - pv;
        cur[t] = st;
        pend[t] = st + pv;
        if (t < wlen) {
            *(int2*)(oe + 2 * (nb0 + t)) = make_int2(st, st + pv);
            dinv[nb0 + t] = rsqrtf((float)(v + 1));   // true count, not padded
        }
    }
    __syncthreads();

    for (int e = t; e < cntb; e += CSR_THREADS) {
        uint32_t p = bp[e];
        int pos = atomicAdd(&cur[p & (BKT_W - 1)], 1);
        csr[pos] = (int)(p >> BKT_SHIFT);
    }
    __syncthreads();
    if (t < BKT_W) {
        int qe = pend[t];
        for (int q = cur[t]; q < qe; q++) csr[q] = n;
    }
}

// ---------------- k_gemm1: layer-1 GEMM, f32 in (x), fp8 out (xw1), dinv-scaled ----------------
__global__ __launch_bounds__(256) void k_gemm1(const float* __restrict__ x,
                                               const ushort_t* __restrict__ Wt,
                                               const float* __restrict__ dinv,
                                               uint8_t* __restrict__ C, int n) {
    __shared__ ushort_t al[64 * 136];
    __shared__ ushort_t wl[128 * 136];
    const int t = threadIdx.x;
    const int l = t & 63;
    const int wave = t >> 6;
    const int lane15 = l & 15;
    const int quad = l >> 4;
    const int m0 = blockIdx.x * 64;
    const int rows = min(64, n - m0);

#pragma unroll
    for (int i = 0; i < 8; i++) {
        int f = t + 256 * i;
        int r = f >> 4, c = f & 15;
        *(uint4*)(&wl[r * 136 + c * 8]) = ((const uint4*)Wt)[f];
    }
    {
        const float4* Ap = (const float4*)(x + (size_t)m0 * 128);
        int nf = rows * 32;
#pragma unroll
        for (int i = 0; i < 8; i++) {
            int f = t + 256 * i;
            float4 vv = make_float4(0.f, 0.f, 0.f, 0.f);
            if (f < nf) vv = Ap[f];
            ushort4 us;
            us.x = f2bf(vv.x); us.y = f2bf(vv.y); us.z = f2bf(vv.z); us.w = f2bf(vv.w);
            int r = f >> 5, c = f & 31;
            *(ushort4*)(&al[r * 136 + c * 4]) = us;
        }
    }
    __syncthreads();

    f32x4 acc[8];
#pragma unroll
    for (int nt = 0; nt < 8; nt++) acc[nt] = (f32x4){0.f, 0.f, 0.f, 0.f};

    const int arow = wave * 16 + lane15;
#pragma unroll
    for (int kt = 0; kt < 4; kt++) {
        bf16x8 af = *(const bf16x8*)(&al[arow * 136 + kt * 32 + quad * 8]);
#pragma unroll
        for (int nt = 0; nt < 8; nt++) {
            bf16x8 bfr = *(const bf16x8*)(&wl[(nt * 16 + lane15) * 136 + kt * 32 + quad * 8]);
            acc[nt] = __builtin_amdgcn_mfma_f32_16x16x32_bf16(af, bfr, acc[nt], 0, 0, 0);
        }
    }

    const int rbase = m0 + wave * 16 + quad * 4;
    float dsc[4];
#pragma unroll
    for (int r = 0; r < 4; r++)
        dsc[r] = (rbase + r < n) ? dinv[rbase + r] : 0.f;
#pragma unroll
    for (int nt = 0; nt < 8; nt++) {
        int c0 = nt * 16 + lane15;
#pragma unroll
        for (int r = 0; r < 4; r += 2) {
            int pk = __builtin_amdgcn_cvt_pk_fp8_f32(acc[nt][r] * dsc[r],
                                                     acc[nt][r + 1] * dsc[r + 1], 0, false);
            int row0 = rbase + r, row1 = rbase + r + 1;
            if (row0 < n) C[(size_t)row0 * 128 + c0] = (uint8_t)pk;
            if (row1 < n) C[(size_t)row1 * 128 + c0] = (uint8_t)(pk >> 8);
        }
    }
}

// ---------------- MFMA GEMM (layer 2): bf16 in (h), fp8 out (xw2), dinv-scaled ----------------
__global__ __launch_bounds__(256) void k_gemm_mfma(const ushort_t* __restrict__ A,
                                                   const ushort_t* __restrict__ Wt,
                                                   const float* __restrict__ dinv,
                                                   uint8_t* __restrict__ C, int n) {
    __shared__ ushort_t al[64 * 136];
    __shared__ ushort_t wl[128 * 136];
    const int t = threadIdx.x;
    const int l = t & 63;
    const int wave = t >> 6;
    const int lane15 = l & 15;
    const int quad = l >> 4;
    const int m0 = blockIdx.x * 64;
    const int rows = min(64, n - m0);

#pragma unroll
    for (int i = 0; i < 8; i++) {
        int f = t + 256 * i;
        int r = f >> 4, c = f & 15;
        *(uint4*)(&wl[r * 136 + c * 8]) = ((const uint4*)Wt)[f];
    }
    {
        const uint4* Ap = (const uint4*)(A + (size_t)m0 * 128);
        int nf = rows * 16;
#pragma unroll
        for (int i = 0; i < 4; i++) {
            int f = t + 256 * i;
            uint4 v = make_uint4(0, 0, 0, 0);
            if (f < nf) v = Ap[f];
            int r = f >> 4, c = f & 15;
            *(uint4*)(&al[r * 136 + c * 8]) = v;
        }
    }
    __syncthreads();

    f32x4 acc[8];
#pragma unroll
    for (int nt = 0; nt < 8; nt++) acc[nt] = (f32x4){0.f, 0.f, 0.f, 0.f};

    const int arow = wave * 16 + lane15;
#pragma unroll
    for (int kt = 0; kt < 4; kt++) {
        bf16x8 af = *(const bf16x8*)(&al[arow * 136 + kt * 32 + quad * 8]);
#pragma unroll
        for (int nt = 0; nt < 8; nt++) {
            bf16x8 bfr = *(const bf16x8*)(&wl[(nt * 16 + lane15) * 136 + kt * 32 + quad * 8]);
            acc[nt] = __builtin_amdgcn_mfma_f32_16x16x32_bf16(af, bfr, acc[nt], 0, 0, 0);
        }
    }

    const int rbase = m0 + wave * 16 + quad * 4;
    float dsc[4];
#pragma unroll
    for (int r = 0; r < 4; r++)
        dsc[r] = (rbase + r < n) ? dinv[rbase + r] : 0.f;
#pragma unroll
    for (int nt = 0; nt < 8; nt++) {
        int c0 = nt * 16 + lane15;
#pragma unroll
        for (int r = 0; r < 4; r += 2) {
            int pk = __builtin_amdgcn_cvt_pk_fp8_f32(acc[nt][r] * dsc[r],
                                                     acc[nt][r + 1] * dsc[r + 1], 0, false);
            int row0 = rbase + r, row1 = rbase + r + 1;
            if (row0 < n) C[(size_t)row0 * 128 + c0] = (uint8_t)pk;
            if (row1 < n) C[(size_t)row1 * 128 + c0] = (uint8_t)(pk >> 8);
        }
    }
}

// ---------------- Aggregation: 4 consecutive nodes/wave, batched headers, csr prefetch --------
// R9: headers (offs,ends) interleaved in oe -> 2 int4 loads for 4 nodes; node j+1's first
// csr int4 prefetched during node j; self-rows loaded upfront. Request-neutral latency fix.
__global__ __launch_bounds__(256) void k_agg(const ushort_t* __restrict__ xw,   // fp8 pairs
                                             const int* __restrict__ oe,
                                             const int* __restrict__ csr,
                                             const float* __restrict__ dinv,
                                             const float* __restrict__ bias,
                                             ushort_t* __restrict__ out, int n,
                                             float* __restrict__ pooled) {
    __shared__ float red[512];
    const int l = threadIdx.x & 63;
    const int wid = (blockIdx.x << 2) | (threadIdx.x >> 6);
    const int v0 = wid << 2;
    const float2 bb = ((const float2*)bias)[l];
    uint32_t* out32 = (uint32_t*)out;
    float psx = 0.f, psy = 0.f;

    if (v0 < n) {
        const int nv = min(4, n - v0);
        // headers for 4 nodes (oe tail zeroed -> safe beyond n)
        const int4* oh = (const int4*)(oe + 2 * v0);
        int4 h0 = oh[0], h1 = oh[1];
        int e_[4], e1_[4];
        e_[0]  = __builtin_amdgcn_readfirstlane(h0.x);
        e1_[0] = __builtin_amdgcn_readfirstlane(h0.y);
        e_[1]  = __builtin_amdgcn_readfirstlane(h0.z);
        e1_[1] = __builtin_amdgcn_readfirstlane(h0.w);
        e_[2]  = __builtin_amdgcn_readfirstlane(h1.x);
        e1_[2] = __builtin_amdgcn_readfirstlane(h1.y);
        e_[3]  = __builtin_amdgcn_readfirstlane(h1.z);
        e1_[3] = __builtin_amdgcn_readfirstlane(h1.w);

        // self rows upfront (independent loads)
        uint32_t sv[4];
#pragma unroll
        for (int j = 0; j < 4; j++)
            sv[j] = (j < nv) ? (uint32_t)xw[(size_t)(v0 + j) * 64 + l] : 0u;

        int4 pf = *(const int4*)(csr + e_[0]);   // first quad of node 0

#pragma unroll
        for (int j = 0; j < 4; j++) {
            if (j >= nv) break;
            const int v = v0 + j;
            int e = e_[j];
            const int e1 = e1_[j];
            int4 pfn;
            if (j < 3) pfn = *(const int4*)(csr + e_[j + 1]);   // prefetch next node

            f32x2 fs = __builtin_amdgcn_cvt_pk_f32_fp8((int)sv[j], false);
            float ax = fs.x, ay = fs.y;

            uint32_t g0 = 0, g1 = 0, g2 = 0, g3 = 0;
            const bool havepf = (e < e1);
            if (havepf) {
                int u0 = __builtin_amdgcn_readfirstlane(pf.x);
                int u1 = __builtin_amdgcn_readfirstlane(pf.y);
                int u2 = __builtin_amdgcn_readfirstlane(pf.z);
                int u3 = __builtin_amdgcn_readfirstlane(pf.w);
                g0 = (uint32_t)xw[(size_t)u0 * 64 + l];
                g1 = (uint32_t)xw[(size_t)u1 * 64 + l];
                g2 = (uint32_t)xw[(size_t)u2 * 64 + l];
                g3 = (uint32_t)xw[(size_t)u3 * 64 + l];
                e += 4;
            }

            for (; e + 15 < e1; e += 16) {
                const int4* c4 = (const int4*)(csr + e);
                int4 w0 = c4[0], w1 = c4[1], w2 = c4[2], w3 = c4[3];
                int u[16];
                u[0]  = __builtin_amdgcn_readfirstlane(w0.x);
                u[1]  = __builtin_amdgcn_readfirstlane(w0.y);
                u[2]  = __builtin_amdgcn_readfirstlane(w0.z);
                u[3]  = __builtin_amdgcn_readfirstlane(w0.w);
                u[4]  = __builtin_amdgcn_readfirstlane(w1.x);
                u[5]  = __builtin_amdgcn_readfirstlane(w1.y);
                u[6]  = __builtin_amdgcn_readfirstlane(w1.z);
                u[7]  = __builtin_amdgcn_readfirstlane(w1.w);
                u[8]  = __builtin_amdgcn_readfirstlane(w2.x);
                u[9]  = __builtin_amdgcn_readfirstlane(w2.y);
                u[10] = __builtin_amdgcn_readfirstlane(w2.z);
                u[11] = __builtin_amdgcn_readfirstlane(w2.w);
                u[12] = __builtin_amdgcn_readfirstlane(w3.x);
                u[13] = __builtin_amdgcn_readfirstlane(w3.y);
                u[14] = __builtin_amdgcn_readfirstlane(w3.z);
                u[15] = __builtin_amdgcn_readfirstlane(w3.w);
                uint32_t p[16];
#pragma unroll
                for (int i = 0; i < 16; i++) p[i] = (uint32_t)xw[(size_t)u[i] * 64 + l];
#pragma unroll
                for (int i = 0; i < 16; i++) {
                    f32x2 f = __builtin_amdgcn_cvt_pk_f32_fp8((int)p[i], false);
                    ax += f.x; ay += f.y;
                }
            }
            for (; e + 7 < e1; e += 8) {
                const int4* c4 = (const int4*)(csr + e);
                int4 w0 = c4[0], w1 = c4[1];
                int u[8];
                u[0] = __builtin_amdgcn_readfirstlane(w0.x);
                u[1] = __builtin_amdgcn_readfirstlane(w0.y);
                u[2] = __builtin_amdgcn_readfirstlane(w0.z);
                u[3] = __builtin_amdgcn_readfirstlane(w0.w);
                u[4] = __builtin_amdgcn_readfirstlane(w1.x);
                u[5] = __builtin_amdgcn_readfirstlane(w1.y);
                u[6] = __builtin_amdgcn_readfirstlane(w1.z);
                u[7] = __builtin_amdgcn_readfirstlane(w1.w);
                uint32_t p[8];
#pragma unroll
                for (int i = 0; i < 8; i++) p[i] = (uint32_t)xw[(size_t)u[i] * 64 + l];
#pragma unroll
                for (int i = 0; i < 8; i++) {
                    f32x2 f = __builtin_amdgcn_cvt_pk_f32_fp8((int)p[i], false);
                    ax += f.x; ay += f.y;
                }
            }
            for (; e + 3 < e1; e += 4) {
                int4 w0 = *(const int4*)(csr + e);
                int u0 = __builtin_amdgcn_readfirstlane(w0.x);
                int u1 = __builtin_amdgcn_readfirstlane(w0.y);
                int u2 = __builtin_amdgcn_readfirstlane(w0.z);
                int u3 = __builtin_amdgcn_readfirstlane(w0.w);
                uint32_t p0 = (uint32_t)xw[(size_t)u0 * 64 + l];
                uint32_t p1 = (uint32_t)xw[(size_t)u1 * 64 + l];
                uint32_t p2 = (uint32_t)xw[(size_t)u2 * 64 + l];
                uint32_t p3 = (uint32_t)xw[(size_t)u3 * 64 + l];
                f32x2 f0 = __builtin_amdgcn_cvt_pk_f32_fp8((int)p0, false);
                f32x2 f1 = __builtin_amdgcn_cvt_pk_f32_fp8((int)p1, false);
                f32x2 f2 = __builtin_amdgcn_cvt_pk_f32_fp8((int)p2, false);
                f32x2 f3 = __builtin_amdgcn_cvt_pk_f32_fp8((int)p3, false);
                ax += f0.x + f1.x + f2.x + f3.x;
                ay += f0.y + f1.y + f2.y + f3.y;
            }

            if (havepf) {
                f32x2 f0 = __builtin_amdgcn_cvt_pk_f32_fp8((int)g0, false);
                f32x2 f1 = __builtin_amdgcn_cvt_pk_f32_fp8((int)g1, false);
                f32x2 f2 = __builtin_amdgcn_cvt_pk_f32_fp8((int)g2, false);
                f32x2 f3 = __builtin_amdgcn_cvt_pk_f32_fp8((int)g3, false);
                ax += f0.x + f1.x + f2.x + f3.x;
                ay += f0.y + f1.y + f2.y + f3.y;
            }

            float dv = dinv[v];
            float ox = fmaxf(fmaf(ax, dv, bb.x), 0.f);
            float oy = fmaxf(fmaf(ay, dv, bb.y), 0.f);
            if (pooled == nullptr) {
                out32[(size_t)v * 64 + l] = ((uint32_t)f2bf(oy) << 16) | (uint32_t)f2bf(ox);
            } else {
                psx += ox; psy += oy;
            }
            pf = pfn;
        }
    }

    if (pooled != nullptr) {
        const int t = threadIdx.x;
        red[t] = psx;
        red[256 + t] = psy;
        __syncthreads();
        if (t < 64) {
            float sx = red[t] + red[t + 64] + red[t + 128] + red[t + 192];
            float sy = red[256 + t] + red[256 + t + 64] + red[256 + t + 128] + red[256 + t + 192];
            float* slice = pooled + (size_t)(blockIdx.x & (PSLICES - 1)) * 128;
            atomicAdd(&slice[2 * t], sx);
            atomicAdd(&slice[2 * t + 1], sy);
        }
    }
}

// ---------------- k_fc: ILP'd slice reduce + LDS-staged FC, one 512-thread block ------
__global__ __launch_bounds__(512) void k_fc(const float* __restrict__ pooled,
                                            const float* __restrict__ Wfc,
                                            const float* __restrict__ bfc,
                                            float* __restrict__ out, float invN) {
    __shared__ f32x4 red4[512];        // 8 KB
    __shared__ float pl[128];
    __shared__ float wf[128 * 128];    // 64 KB
    const int t = threadIdx.x;
    const int q = t & 31;              // feature quad (features 4q..4q+3)
    const int g = t >> 5;              // slice group, 16 groups

    const f32x4* W4 = (const f32x4*)Wfc;
    f32x4* wf4 = (f32x4*)wf;
#pragma unroll
    for (int i = 0; i < 8; i++) wf4[t + 512 * i] = W4[t + 512 * i];

    const f32x4* P = (const f32x4*)pooled;   // [PSLICES][32]
    f32x4 a0 = (f32x4){0.f, 0.f, 0.f, 0.f}, a1 = a0, a2 = a0, a3 = a0;
#pragma unroll
    for (int k = 0; k < 16; k++) {
        a0 += P[(size_t)(g + 16 * (4 * k + 0)) * 32 + q];
        a1 += P[(size_t)(g + 16 * (4 * k + 1)) * 32 + q];
        a2 += P[(size_t)(g + 16 * (4 * k + 2)) * 32 + q];
        a3 += P[(size_t)(g + 16 * (4 * k + 3)) * 32 + q];
    }
    red4[t] = (a0 + a1) + (a2 + a3);
    __syncthreads();
    if (t < 32) {
        f32x4 s = red4[t];
#pragma unroll
        for (int g2 = 1; g2 < 16; g2++) s += red4[g2 * 32 + t];
        pl[4 * t + 0] = s[0] * invN;
        pl[4 * t + 1] = s[1] * invN;
        pl[4 * t + 2] = s[2] * invN;
        pl[4 * t + 3] = s[3] * invN;
    }
    __syncthreads();
    if (t < 128) {
        float o = bfc[t];
#pragma unroll 8
        for (int k = 0; k < 128; k++) o = fmaf(pl[k], wf[k * 128 + t], o);
        out[t] = o;
    }
}

// ---------------- launcher ----------------
extern "C" void kernel_launch(void* const* d_in, const int* in_sizes, int n_in,
                              void* d_out, int out_size, void* d_ws, size_t ws_size,
                              hipStream_t stream) {
    const float* x    = (const float*)d_in[0];
    const int*   ei   = (const int*)d_in[1];
    const float* W1   = (const float*)d_in[2];
    const float* b1   = (const float*)d_in[3];
    const float* W2   = (const float*)d_in[4];
    const float* b2   = (const float*)d_in[5];
    const float* Wfc  = (const float*)d_in[6];
    const float* bfc  = (const float*)d_in[7];
    float*       out  = (float*)d_out;

    const int n = in_sizes[0] / 128;
    const int E = in_sizes[1] / 2;
    const int* src = ei;
    const int* dst = ei + E;
    const int NB = (n + BKT_W - 1) >> BKT_SHIFT;   // 782

    char* w = (char*)d_ws;
    uint8_t*  xwq = (uint8_t*)w;  w += (size_t)(n + 1) * 128;           // fp8 [n+1][128], row n = zeros
    ushort_t* h   = (ushort_t*)w; w += (size_t)n * 128 * sizeof(ushort_t);
    int*      csr = (int*)w;      w += ((size_t)NB * CSTRIDE + 64) * sizeof(int);
    uint32_t* bpack = (uint32_t*)w; w += (size_t)NB * BCAP * sizeof(uint32_t);
    float* dinv = (float*)w;  w += (size_t)n * sizeof(float);
    int*   oe   = (int*)w;    w += (size_t)2 * (n + 8) * sizeof(int);
    w = (char*)(((uintptr_t)w + 127) & ~(uintptr_t)127);
    int*   bcnt  = (int*)w;   w += NB_MAX * sizeof(int);
    float* pooled = (float*)w; w += (size_t)PSLICES * 128 * sizeof(float);
    ushort_t* Wt1 = (ushort_t*)w; w += 16384 * sizeof(ushort_t);
    ushort_t* Wt2 = (ushort_t*)w; w += 16384 * sizeof(ushort_t);

    const int ntiles64 = (n + 63) / 64;
    const float invN = 1.0f / (float)n;

    kW_init<<<80, 256, 0, stream>>>(W1, W2, Wt1, Wt2, bcnt, pooled, xwq, oe, n);
    kB_bucket<<<(E + KB_CHUNK - 1) / KB_CHUNK, KB_THREADS, 0, stream>>>(src, dst, E, NB, bcnt, bpack);
    kC_csr<<<NB, CSR_THREADS, 0, stream>>>(bpack, bcnt, NB, n, dinv, oe, csr);
    k_gemm1<<<ntiles64, 256, 0, stream>>>(x, Wt1, dinv, xwq, n);

    k_agg<<<8192, 256, 0, stream>>>((const ushort_t*)xwq, oe, csr, dinv, b1, h, n, nullptr);
    k_gemm_mfma<<<ntiles64, 256, 0, stream>>>(h, Wt2, dinv, xwq, n);
    k_agg<<<8192, 256, 0, stream>>>((const ushort_t*)xwq, oe, csr, dinv, b2, h, n, pooled);

    k_fc<<<1, 512, 0, stream>>>(pooled, Wfc, bfc, out, invN);
}